// Round 1
// baseline (1487.544 us; speedup 1.0000x reference)
//
#include <hip/hip_runtime.h>
#include <math.h>

#define T_ 8
#define B_ 4
#define C_ 128
#define HW_ 9216        // 96*96
#define IN_HW_ 147456   // 384*384

// ---------------------------------------------------------------------------
// Bilinear antialias resize 384 -> 96: separable 8-tap triangle filter.
// sample center c = 4*i + 1.5; taps j = 4*i - 2 + k, k=0..7
// raw w_k = 1 - |k-3.5|/4 = {.125,.375,.625,.875,.875,.625,.375,.125}, sum 4.
// Edge i=0: taps k=0,1 invalid -> renormalize over sum 3.5 (symmetric i=95).
// Double precision: the >0.5 threshold sits in the bulk of the value
// distribution; we must match the numpy/f64 reference on knife-edge pixels.
// ---------------------------------------------------------------------------
__device__ __forceinline__ double resize_px(const float* __restrict__ img, int y, int x) {
  static const double wm[8]  = {0.03125, 0.09375, 0.15625, 0.21875,
                                0.21875, 0.15625, 0.09375, 0.03125};
  static const double w0[8]  = {0.0, 0.0, 0.625/3.5, 0.875/3.5,
                                0.875/3.5, 0.625/3.5, 0.375/3.5, 0.125/3.5};
  static const double w95[8] = {0.125/3.5, 0.375/3.5, 0.625/3.5, 0.875/3.5,
                                0.875/3.5, 0.625/3.5, 0.0, 0.0};
  const double* wy = (y == 0) ? w0 : (y == 95 ? w95 : wm);
  const double* wx = (x == 0) ? w0 : (x == 95 ? w95 : wm);
  double acc = 0.0;
#pragma unroll
  for (int ky = 0; ky < 8; ++ky) {
    double wyv = wy[ky];
    if (wyv == 0.0) continue;
    int jy = 4 * y - 2 + ky;
    const float* row = img + jy * 384;
    double ra = 0.0;
#pragma unroll
    for (int kx = 0; kx < 8; ++kx) {
      double wxv = wx[kx];
      if (wxv == 0.0) continue;
      int jx = 4 * x - 2 + kx;
      ra += wxv * (double)row[jx];
    }
    acc += wyv * ra;
  }
  return acc;
}

__device__ __forceinline__ float block_reduce_sum_256(float v) {
  __shared__ float s[256];
  s[threadIdx.x] = v;
  __syncthreads();
  for (int k = 128; k > 0; k >>= 1) {
    if (threadIdx.x < (unsigned)k) s[threadIdx.x] += s[threadIdx.x + k];
    __syncthreads();
  }
  return s[0];
}

// tv[b,p] = binarized resize of tvmap[b]  (grid: B_ blocks x 256)
__global__ void k_tv(const float* __restrict__ tvmap, float* __restrict__ tv) {
  int b = blockIdx.x;
  const float* img = tvmap + (size_t)b * IN_HW_;
  for (int p = threadIdx.x; p < HW_; p += 256) {
    int y = p / 96, x = p % 96;
    tv[(size_t)b * HW_ + p] = (resize_px(img, y, x) > 0.5) ? 1.0f : 0.0f;
  }
}

// rv[tb,p], vm[tb,p] = rv*tv, v_sum[tb]  (grid: T_*B_ blocks x 256)
__global__ void k_rv(const float* __restrict__ rvmaps, const float* __restrict__ tv,
                     float* __restrict__ rv, float* __restrict__ vm,
                     float* __restrict__ v_sum) {
  int tb = blockIdx.x;          // t*B + b
  int b = tb % B_;
  const float* img = rvmaps + (size_t)tb * IN_HW_;
  float local = 0.f;
  for (int p = threadIdx.x; p < HW_; p += 256) {
    int y = p / 96, x = p % 96;
    float rvv = (resize_px(img, y, x) > 0.5) ? 1.0f : 0.0f;
    float vmv = rvv * tv[(size_t)b * HW_ + p];
    rv[(size_t)tb * HW_ + p] = rvv;
    vm[(size_t)tb * HW_ + p] = vmv;
    local += vmv;
  }
  float s = block_reduce_sum_256(local);
  if (threadIdx.x == 0) v_sum[tb] = s;
}

// gs_part[(tb)*C + c] = sum_p vm[tb,p]*t_feat[b,c,p]*r_feats[t,b,c,p]
// grid: T_*B_*C_ blocks x 256, float4 streaming (main read pass #1)
__global__ __launch_bounds__(256) void k_gs(const float* __restrict__ values,
                                            const float* __restrict__ vm,
                                            float* __restrict__ gs_part) {
  int blk = blockIdx.x;         // (t*B+b)*C + c
  int c  = blk % C_;
  int tb = blk / C_;
  int b  = tb % B_;
  // r_feats[t,b,c] = values[((1+t)*B + b)*C*HW + c*HW] ; (1+t)*B+b = B_+tb
  const float4* rf  = (const float4*)(values + ((size_t)(B_ + tb) * C_ + c) * HW_);
  const float4* tf  = (const float4*)(values + ((size_t)b * C_ + c) * HW_);
  const float4* vmp = (const float4*)(vm + (size_t)tb * HW_);
  float acc = 0.f;
  for (int i = threadIdx.x; i < HW_ / 4; i += 256) {
    float4 m = vmp[i];
    float4 a = tf[i];
    float4 r = rf[i];
    acc += m.x * a.x * r.x + m.y * a.y * r.y + m.z * a.z * r.z + m.w * a.w * r.w;
  }
  float s = block_reduce_sum_256(acc);
  if (threadIdx.x == 0) gs_part[blk] = s;
}

// gs[tb] = where(empty,0,sum_c part)/(v_sum+empty)/C ; also to d_out tail
__global__ void k_gsfin(const float* __restrict__ gs_part, const float* __restrict__ v_sum,
                        float* __restrict__ gs, float* __restrict__ out_gs) {
  int i = threadIdx.x;
  if (i < T_ * B_) {
    float s = 0.f;
    for (int c = 0; c < C_; ++c) s += gs_part[i * C_ + c];
    float vs = v_sum[i];
    bool empty = vs < 1e-4f;
    float g = (empty ? 0.f : s) / (vs + (empty ? 1.f : 0.f)) / (float)C_;
    gs[i] = g;
    out_gs[i] = g;
  }
}

// Epilogue: per pixel softmax-match over t, then c_out, c_mask, t_feat copy.
// grid: (16 ctiles of 8 channels, 9 ptiles of 1024 px, B_) x 256 threads,
// 4 px per thread (float4).
__global__ __launch_bounds__(256) void k_epi(const float* __restrict__ values,
                                             const float* __restrict__ rv,
                                             const float* __restrict__ gs,
                                             float* __restrict__ out,
                                             float* __restrict__ out_cmask) {
  int ctile = blockIdx.x;       // 0..15
  int ptile = blockIdx.y;       // 0..8
  int b     = blockIdx.z;       // 0..3
  __shared__ float gsh[T_];
  if (threadIdx.x < T_) gsh[threadIdx.x] = gs[threadIdx.x * B_ + b];
  __syncthreads();

  int p0 = ptile * 1024 + threadIdx.x * 4;

  float4 rv4[T_];
#pragma unroll
  for (int t = 0; t < T_; ++t)
    rv4[t] = *(const float4*)(rv + ((size_t)(t * B_ + b)) * HW_ + p0);

  float cm[T_][4];
  float cmask[4];
#pragma unroll
  for (int j = 0; j < 4; ++j) {
    float mv[T_];
    float mx = -1e30f;
#pragma unroll
    for (int t = 0; t < T_; ++t) {
      float rvv = ((const float*)&rv4[t])[j];
      mv[t] = gsh[t] * rvv;
      mx = fmaxf(mx, mv[t]);
    }
    float e[T_];
    float ms = 0.f;
#pragma unroll
    for (int t = 0; t < T_; ++t) {
      float rvv = ((const float*)&rv4[t])[j];
      e[t] = expf(mv[t] - mx) * rvv;
      ms += e[t];
    }
    if (ms < 1e-4f) ms += 1.f;
    float inv = 1.f / ms;
    float cs = 0.f;
#pragma unroll
    for (int t = 0; t < T_; ++t) {
      cm[t][j] = e[t] * inv;
      cs += cm[t][j] * ((const float*)&rv4[t])[j];
    }
    cmask[j] = 1.f - cs;
  }

  size_t outb = (size_t)b * 257 * HW_;
#pragma unroll 1
  for (int cc = 0; cc < 8; ++cc) {
    int c = ctile * 8 + cc;
    // t_feat passthrough (channels 0..127)
    float4 tf = *(const float4*)(values + ((size_t)b * C_ + c) * HW_ + p0);
    *(float4*)(out + outb + (size_t)c * HW_ + p0) = tf;
    // c_out (channels 128..255)
    float4 acc = {0.f, 0.f, 0.f, 0.f};
#pragma unroll
    for (int t = 0; t < T_; ++t) {
      const float4 r = *(const float4*)(values +
          ((size_t)((1 + t) * B_ + b) * C_ + c) * HW_ + p0);
      acc.x += cm[t][0] * r.x;
      acc.y += cm[t][1] * r.y;
      acc.z += cm[t][2] * r.z;
      acc.w += cm[t][3] * r.w;
    }
    *(float4*)(out + outb + (size_t)(C_ + c) * HW_ + p0) = acc;
  }
  if (ctile == 0) {
    float4 cmv = {cmask[0], cmask[1], cmask[2], cmask[3]};
    *(float4*)(out + outb + (size_t)256 * HW_ + p0) = cmv;           // channel 256
    *(float4*)(out_cmask + (size_t)b * HW_ + p0) = cmv;              // output 2
  }
}

extern "C" void kernel_launch(void* const* d_in, const int* in_sizes, int n_in,
                              void* d_out, int out_size, void* d_ws, size_t ws_size,
                              hipStream_t stream) {
  const float* values = (const float*)d_in[0];   // (9,4,128,96,96)
  const float* tvmap  = (const float*)d_in[1];   // (4,1,384,384)
  const float* rvmaps = (const float*)d_in[2];   // (8,4,1,384,384)
  float* out = (float*)d_out;

  // workspace layout (floats)
  float* ws      = (float*)d_ws;
  float* tv      = ws;                       // B_*HW_        = 36864
  float* rv      = tv + (size_t)B_ * HW_;    // T_*B_*HW_     = 294912
  float* vm      = rv + (size_t)T_ * B_ * HW_;
  float* gs_part = vm + (size_t)T_ * B_ * HW_;   // T_*B_*C_  = 4096
  float* v_sum   = gs_part + T_ * B_ * C_;       // 32
  float* gsar    = v_sum + T_ * B_;              // 32

  // output layout: out(4,257,96,96) | c_mask(4,1,96,96) | gs(8,4)
  float* out_cmask = out + (size_t)B_ * 257 * HW_;
  float* out_gs    = out_cmask + (size_t)B_ * HW_;

  hipLaunchKernelGGL(k_tv,    dim3(B_),            dim3(256), 0, stream, tvmap, tv);
  hipLaunchKernelGGL(k_rv,    dim3(T_ * B_),       dim3(256), 0, stream, rvmaps, tv, rv, vm, v_sum);
  hipLaunchKernelGGL(k_gs,    dim3(T_ * B_ * C_),  dim3(256), 0, stream, values, vm, gs_part);
  hipLaunchKernelGGL(k_gsfin, dim3(1),             dim3(64),  0, stream, gs_part, v_sum, gsar, out_gs);
  hipLaunchKernelGGL(k_epi,   dim3(16, 9, B_),     dim3(256), 0, stream, values, rv, gsar, out, out_cmask);
}

// Round 2
// 345.988 us; speedup vs baseline: 4.2994x; 4.2994x over previous
//
#include <hip/hip_runtime.h>
#include <math.h>

#define T_ 8
#define B_ 4
#define C_ 128
#define HW_ 9216        // 96*96
#define IN_HW_ 147456   // 384*384

// ---------------------------------------------------------------------------
// Bilinear antialias resize 384 -> 96: separable 8-tap triangle filter.
// sample center c = 4*i + 1.5; taps j = 4*i - 2 + k, k=0..7
// raw w_k = 1 - |k-3.5|/4 = {.125,.375,.625,.875,.875,.625,.375,.125}, sum 4.
// Edge i=0: taps k=0,1 invalid -> renormalize over sum 3.5 (symmetric i=95).
// Double precision: the >0.5 threshold sits in the bulk of the value
// distribution; we must match the numpy/f64 reference on knife-edge pixels.
// ---------------------------------------------------------------------------
__device__ __forceinline__ double resize_px(const float* __restrict__ img, int y, int x) {
  static const double wm[8]  = {0.03125, 0.09375, 0.15625, 0.21875,
                                0.21875, 0.15625, 0.09375, 0.03125};
  static const double w0[8]  = {0.0, 0.0, 0.625/3.5, 0.875/3.5,
                                0.875/3.5, 0.625/3.5, 0.375/3.5, 0.125/3.5};
  static const double w95[8] = {0.125/3.5, 0.375/3.5, 0.625/3.5, 0.875/3.5,
                                0.875/3.5, 0.625/3.5, 0.0, 0.0};
  const double* wy = (y == 0) ? w0 : (y == 95 ? w95 : wm);
  const double* wx = (x == 0) ? w0 : (x == 95 ? w95 : wm);
  double acc = 0.0;
#pragma unroll
  for (int ky = 0; ky < 8; ++ky) {
    double wyv = wy[ky];
    if (wyv == 0.0) continue;
    int jy = 4 * y - 2 + ky;
    const float* row = img + jy * 384;
    double ra = 0.0;
#pragma unroll
    for (int kx = 0; kx < 8; ++kx) {
      double wxv = wx[kx];
      if (wxv == 0.0) continue;
      int jx = 4 * x - 2 + kx;
      ra += wxv * (double)row[jx];
    }
    acc += wyv * ra;
  }
  return acc;
}

__device__ __forceinline__ float block_reduce_sum_256(float v) {
  __shared__ float s[256];
  s[threadIdx.x] = v;
  __syncthreads();
  for (int k = 128; k > 0; k >>= 1) {
    if (threadIdx.x < (unsigned)k) s[threadIdx.x] += s[threadIdx.x + k];
    __syncthreads();
  }
  return s[0];
}

__global__ void k_init(float* __restrict__ v_sum) {
  if (threadIdx.x < T_ * B_) v_sum[threadIdx.x] = 0.f;
}

// tv[b,p] = binarized resize of tvmap[b]. grid: (HW/256, B), 1 px/thread.
__global__ void k_tv(const float* __restrict__ tvmap, float* __restrict__ tv) {
  int b = blockIdx.y;
  int p = blockIdx.x * 256 + threadIdx.x;
  const float* img = tvmap + (size_t)b * IN_HW_;
  int y = p / 96, x = p % 96;
  tv[(size_t)b * HW_ + p] = (resize_px(img, y, x) > 0.5) ? 1.0f : 0.0f;
}

// rv[tb,p], vm[tb,p] = rv*tv, v_sum[tb] += block partial.
// grid: (HW/256, T*B), 1 px/thread.
__global__ void k_rv(const float* __restrict__ rvmaps, const float* __restrict__ tv,
                     float* __restrict__ rv, float* __restrict__ vm,
                     float* __restrict__ v_sum) {
  int tb = blockIdx.y;          // t*B + b
  int b = tb % B_;
  int p = blockIdx.x * 256 + threadIdx.x;
  const float* img = rvmaps + (size_t)tb * IN_HW_;
  int y = p / 96, x = p % 96;
  float rvv = (resize_px(img, y, x) > 0.5) ? 1.0f : 0.0f;
  float vmv = rvv * tv[(size_t)b * HW_ + p];
  rv[(size_t)tb * HW_ + p] = rvv;
  vm[(size_t)tb * HW_ + p] = vmv;
  float s = block_reduce_sum_256(vmv);
  if (threadIdx.x == 0) atomicAdd(&v_sum[tb], s);
}

// gs_part[(tb)*C + c] = sum_p vm[tb,p]*t_feat[b,c,p]*r_feats[t,b,c,p]
// grid: T_*B_*C_ blocks x 256, float4 streaming (main read pass #1)
__global__ __launch_bounds__(256) void k_gs(const float* __restrict__ values,
                                            const float* __restrict__ vm,
                                            float* __restrict__ gs_part) {
  int blk = blockIdx.x;         // (t*B+b)*C + c
  int c  = blk % C_;
  int tb = blk / C_;
  int b  = tb % B_;
  const float4* rf  = (const float4*)(values + ((size_t)(B_ + tb) * C_ + c) * HW_);
  const float4* tf  = (const float4*)(values + ((size_t)b * C_ + c) * HW_);
  const float4* vmp = (const float4*)(vm + (size_t)tb * HW_);
  float acc = 0.f;
  for (int i = threadIdx.x; i < HW_ / 4; i += 256) {
    float4 m = vmp[i];
    float4 a = tf[i];
    float4 r = rf[i];
    acc += m.x * a.x * r.x + m.y * a.y * r.y + m.z * a.z * r.z + m.w * a.w * r.w;
  }
  float s = block_reduce_sum_256(acc);
  if (threadIdx.x == 0) gs_part[blk] = s;
}

// gs[tb] = where(empty,0,sum_c part)/(v_sum+empty)/C ; also to d_out tail
__global__ void k_gsfin(const float* __restrict__ gs_part, const float* __restrict__ v_sum,
                        float* __restrict__ gs, float* __restrict__ out_gs) {
  int i = threadIdx.x;
  if (i < T_ * B_) {
    float s = 0.f;
    for (int c = 0; c < C_; ++c) s += gs_part[i * C_ + c];
    float vs = v_sum[i];
    bool empty = vs < 1e-4f;
    float g = (empty ? 0.f : s) / (vs + (empty ? 1.f : 0.f)) / (float)C_;
    gs[i] = g;
    out_gs[i] = g;
  }
}

// Epilogue: per pixel softmax-match over t, then c_out, c_mask, t_feat copy.
// grid: (16 ctiles of 8 channels, 9 ptiles of 1024 px, B_) x 256 threads,
// 4 px per thread (float4).
__global__ __launch_bounds__(256) void k_epi(const float* __restrict__ values,
                                             const float* __restrict__ rv,
                                             const float* __restrict__ gs,
                                             float* __restrict__ out,
                                             float* __restrict__ out_cmask) {
  int ctile = blockIdx.x;       // 0..15
  int ptile = blockIdx.y;       // 0..8
  int b     = blockIdx.z;       // 0..3
  __shared__ float gsh[T_];
  if (threadIdx.x < T_) gsh[threadIdx.x] = gs[threadIdx.x * B_ + b];
  __syncthreads();

  int p0 = ptile * 1024 + threadIdx.x * 4;

  float4 rv4[T_];
#pragma unroll
  for (int t = 0; t < T_; ++t)
    rv4[t] = *(const float4*)(rv + ((size_t)(t * B_ + b)) * HW_ + p0);

  float cm[T_][4];
  float cmask[4];
#pragma unroll
  for (int j = 0; j < 4; ++j) {
    float mv[T_];
    float mx = -1e30f;
#pragma unroll
    for (int t = 0; t < T_; ++t) {
      float rvv = ((const float*)&rv4[t])[j];
      mv[t] = gsh[t] * rvv;
      mx = fmaxf(mx, mv[t]);
    }
    float e[T_];
    float ms = 0.f;
#pragma unroll
    for (int t = 0; t < T_; ++t) {
      float rvv = ((const float*)&rv4[t])[j];
      e[t] = expf(mv[t] - mx) * rvv;
      ms += e[t];
    }
    if (ms < 1e-4f) ms += 1.f;
    float inv = 1.f / ms;
    float cs = 0.f;
#pragma unroll
    for (int t = 0; t < T_; ++t) {
      cm[t][j] = e[t] * inv;
      cs += cm[t][j] * ((const float*)&rv4[t])[j];
    }
    cmask[j] = 1.f - cs;
  }

  size_t outb = (size_t)b * 257 * HW_;
#pragma unroll 1
  for (int cc = 0; cc < 8; ++cc) {
    int c = ctile * 8 + cc;
    // t_feat passthrough (channels 0..127)
    float4 tf = *(const float4*)(values + ((size_t)b * C_ + c) * HW_ + p0);
    *(float4*)(out + outb + (size_t)c * HW_ + p0) = tf;
    // c_out (channels 128..255)
    float4 acc = {0.f, 0.f, 0.f, 0.f};
#pragma unroll
    for (int t = 0; t < T_; ++t) {
      const float4 r = *(const float4*)(values +
          ((size_t)((1 + t) * B_ + b) * C_ + c) * HW_ + p0);
      acc.x += cm[t][0] * r.x;
      acc.y += cm[t][1] * r.y;
      acc.z += cm[t][2] * r.z;
      acc.w += cm[t][3] * r.w;
    }
    *(float4*)(out + outb + (size_t)(C_ + c) * HW_ + p0) = acc;
  }
  if (ctile == 0) {
    float4 cmv = {cmask[0], cmask[1], cmask[2], cmask[3]};
    *(float4*)(out + outb + (size_t)256 * HW_ + p0) = cmv;           // channel 256
    *(float4*)(out_cmask + (size_t)b * HW_ + p0) = cmv;              // output 2
  }
}

extern "C" void kernel_launch(void* const* d_in, const int* in_sizes, int n_in,
                              void* d_out, int out_size, void* d_ws, size_t ws_size,
                              hipStream_t stream) {
  const float* values = (const float*)d_in[0];   // (9,4,128,96,96)
  const float* tvmap  = (const float*)d_in[1];   // (4,1,384,384)
  const float* rvmaps = (const float*)d_in[2];   // (8,4,1,384,384)
  float* out = (float*)d_out;

  // workspace layout (floats)
  float* ws      = (float*)d_ws;
  float* tv      = ws;                       // B_*HW_        = 36864
  float* rv      = tv + (size_t)B_ * HW_;    // T_*B_*HW_     = 294912
  float* vm      = rv + (size_t)T_ * B_ * HW_;
  float* gs_part = vm + (size_t)T_ * B_ * HW_;   // T_*B_*C_  = 4096
  float* v_sum   = gs_part + T_ * B_ * C_;       // 32
  float* gsar    = v_sum + T_ * B_;              // 32

  // output layout: out(4,257,96,96) | c_mask(4,1,96,96) | gs(8,4)
  float* out_cmask = out + (size_t)B_ * 257 * HW_;
  float* out_gs    = out_cmask + (size_t)B_ * HW_;

  hipLaunchKernelGGL(k_init,  dim3(1),                dim3(64),  0, stream, v_sum);
  hipLaunchKernelGGL(k_tv,    dim3(HW_ / 256, B_),    dim3(256), 0, stream, tvmap, tv);
  hipLaunchKernelGGL(k_rv,    dim3(HW_ / 256, T_ * B_), dim3(256), 0, stream, rvmaps, tv, rv, vm, v_sum);
  hipLaunchKernelGGL(k_gs,    dim3(T_ * B_ * C_),     dim3(256), 0, stream, values, vm, gs_part);
  hipLaunchKernelGGL(k_gsfin, dim3(1),                dim3(64),  0, stream, gs_part, v_sum, gsar, out_gs);
  hipLaunchKernelGGL(k_epi,   dim3(16, 9, B_),        dim3(256), 0, stream, values, rv, gsar, out, out_cmask);
}